// Round 26
// baseline (208.537 us; speedup 1.0000x reference)
//
#include <hip/hip_runtime.h>

#define NN 50000
#define NE 1600000
#define IND 256
#define OUTD 64
#define NH 4
#define EPB 4096
#define NBLKP 391   // ceil(NE/EPB)
#define NBUCK 196   // ceil(NN/256)
#define NTILE 3125  // NN/16

typedef __attribute__((ext_vector_type(8))) short short8;
typedef __attribute__((ext_vector_type(4))) float f32x4;

__device__ __forceinline__ unsigned short f2bf(float x) {
    unsigned int u = __float_as_uint(x);
    u = (u + 0x7FFFu + ((u >> 16) & 1u)) >> 16;   // RNE
    return (unsigned short)u;
}
__device__ __forceinline__ float bf2f(unsigned short u) {
    return __uint_as_float((unsigned int)u << 16);
}

// ---- Wtf[hd][nt][ks][lane][e] = bf16(W[hd][ks*32+(lane>>4)*8+e][nt*16+(lane&15)]) ----
__global__ __launch_bounds__(256) void k_wt(const float* __restrict__ W, unsigned short* __restrict__ Wtf,
                                            const float4* __restrict__ e4, float4* __restrict__ oute4) {
    int t = blockIdx.x * 256 + threadIdx.x;       // 65536
    int e = t & 7;
    int lane = (t >> 3) & 63;
    int ks = (t >> 9) & 7;
    int nt = (t >> 12) & 3;
    int hd = (t >> 14) & 3;
    int k = ks * 32 + (lane >> 4) * 8 + e;
    int d = nt * 16 + (lane & 15);
    Wtf[t] = f2bf(W[hd * IND * OUTD + k * OUTD + d]);
    for (int i = t; i < NE / 4; i += 65536) oute4[i] = e4[i];
}

// ---- A pre-transpose: hbf[tile][ks][lane][e] = bf16(h[tile*16+(lane&15)][ks*32+(lane>>4)*8+e]*norm) ----
// coalesced reads (8 consecutive floats/thread), 16B scattered writes with full 64B-line utilization
__global__ __launch_bounds__(256) void k_conv(const float* __restrict__ h, const float* __restrict__ norm,
                                              unsigned short* __restrict__ hbf) {
    int t = blockIdx.x * 256 + threadIdx.x;       // 0..1,599,999
    int row = t >> 5;
    int col = (t & 31) << 3;
    float nmv = norm[row];
    const float4* hp = (const float4*)(h + (size_t)row * IND + col);
    float4 x0 = hp[0], x1 = hp[1];
    short8 r;
    r[0] = (short)f2bf(x0.x * nmv); r[1] = (short)f2bf(x0.y * nmv);
    r[2] = (short)f2bf(x0.z * nmv); r[3] = (short)f2bf(x0.w * nmv);
    r[4] = (short)f2bf(x1.x * nmv); r[5] = (short)f2bf(x1.y * nmv);
    r[6] = (short)f2bf(x1.z * nmv); r[7] = (short)f2bf(x1.w * nmv);
    int tile = row >> 4, r16 = row & 15;
    int ks = col >> 5, kg = (col >> 3) & 3;
    *((short8*)hbf + (size_t)(tile * 8 + ks) * 64 + kg * 16 + r16) = r;
}

// ---- fused GEMM: fragment-major A and B, no LDS staging, no barrier in main loop ----
__global__ __launch_bounds__(256) void k_gmm(const unsigned short* __restrict__ hbf,
                                             const unsigned short* __restrict__ Wtf, const float* __restrict__ a,
                                             unsigned short* __restrict__ zb,
                                             float* __restrict__ ssrc, float* __restrict__ sdst) {
    __shared__ unsigned short ldsE[4][16 * 80];   // epilogue transpose
    const int tid = threadIdx.x;
    const int lane = tid & 63;
    const int wv = tid >> 6;                      // head index
    const int m0 = blockIdx.x * 32;
    const int c0 = wv * 64;
    const int r16 = lane & 15, kg = lane >> 4;

    int tile0 = blockIdx.x * 2;
    int tile1 = tile0 + 1; if (tile1 > NTILE - 1) tile1 = NTILE - 1;
    const short8* ap0 = (const short8*)hbf + (size_t)tile0 * 8 * 64 + lane;
    const short8* ap1 = (const short8*)hbf + (size_t)tile1 * 8 * 64 + lane;
    const short8* bfp = (const short8*)(Wtf) + (size_t)wv * 4 * 8 * 64;   // head base, fragment-major

    f32x4 acc[2][4] = {};
    #pragma unroll
    for (int ks = 0; ks < 8; ++ks) {
        short8 av0 = ap0[ks * 64];
        short8 av1 = ap1[ks * 64];
        #pragma unroll
        for (int nt = 0; nt < 4; ++nt) {
            short8 cb = bfp[(nt * 8 + ks) * 64 + lane];
            acc[0][nt] = __builtin_amdgcn_mfma_f32_16x16x32_bf16(av0, cb, acc[0][nt], 0, 0, 0);
            acc[1][nt] = __builtin_amdgcn_mfma_f32_16x16x32_bf16(av1, cb, acc[1][nt], 0, 0, 0);
        }
    }

    float asrc[4], adst[4];
    #pragma unroll
    for (int j = 0; j < 4; ++j) {
        asrc[j] = a[wv * 128 + j * 16 + r16];
        adst[j] = a[wv * 128 + 64 + j * 16 + r16];
    }
    #pragma unroll
    for (int mt = 0; mt < 2; ++mt) {
        #pragma unroll
        for (int r = 0; r < 4; ++r) {
            int row = m0 + mt * 16 + kg * 4 + r;  // D: row=(lane>>4)*4+reg, col=lane&15
            unsigned short q0 = f2bf(acc[mt][0][r]);
            unsigned short q1 = f2bf(acc[mt][1][r]);
            unsigned short q2 = f2bf(acc[mt][2][r]);
            unsigned short q3 = f2bf(acc[mt][3][r]);
            float ps = bf2f(q0) * asrc[0] + bf2f(q1) * asrc[1] + bf2f(q2) * asrc[2] + bf2f(q3) * asrc[3];
            float pd = bf2f(q0) * adst[0] + bf2f(q1) * adst[1] + bf2f(q2) * adst[2] + bf2f(q3) * adst[3];
            #pragma unroll
            for (int off = 1; off < 16; off <<= 1) {
                ps += __shfl_xor(ps, off);
                pd += __shfl_xor(pd, off);
            }
            unsigned short* lp = &ldsE[wv][(kg * 4 + r) * 80];
            lp[ 0 + r16] = q0;
            lp[16 + r16] = q1;
            lp[32 + r16] = q2;
            lp[48 + r16] = q3;
            if (row < NN && r16 == 0) {
                ssrc[(row << 2) + wv] = ps;
                sdst[(row << 2) + wv] = pd;
            }
        }
        asm volatile("s_waitcnt lgkmcnt(0)" ::: "memory");
        __builtin_amdgcn_sched_barrier(0);
        #pragma unroll
        for (int hf = 0; hf < 2; ++hf) {
            int lrow = hf * 8 + (lane >> 3);
            int chunk = lane & 7;
            short8 v = *(const short8*)&ldsE[wv][lrow * 80 + chunk * 8];
            int grow = m0 + mt * 16 + lrow;
            if (grow < NN)
                *(short8*)(zb + (size_t)grow * IND + c0 + chunk * 8) = v;
        }
        __builtin_amdgcn_sched_barrier(0);
    }
}

// ---- partition step 1: per-block histogram over 196 coarse buckets (dst>>8) ----
__global__ __launch_bounds__(256) void k_phist(const int* __restrict__ dst, int* __restrict__ bh) {
    __shared__ int lh[NBUCK];
    int tid = threadIdx.x;
    if (tid < NBUCK) lh[tid] = 0;
    __syncthreads();
    int base = blockIdx.x * EPB;
    for (int i = tid; i < EPB; i += 256) {
        int ed = base + i;
        if (ed < NE) atomicAdd(&lh[dst[ed] >> 8], 1);
    }
    __syncthreads();
    if (tid < NBUCK) bh[blockIdx.x * NBUCK + tid] = lh[tid];
}

// ---- partition step 2a: per-bucket column scan (196 blocks, parallel) ----
__global__ __launch_bounds__(256) void k_poffA(const int* __restrict__ bh, int* __restrict__ goff,
                                               int* __restrict__ colsum) {
    __shared__ int wsum[4];
    int t = blockIdx.x;                        // bucket
    int tid = threadIdx.x;
    int b0 = tid * 2, b1 = tid * 2 + 1;
    int v0 = (b0 < NBLKP) ? bh[b0 * NBUCK + t] : 0;
    int v1 = (b1 < NBLKP) ? bh[b1 * NBUCK + t] : 0;
    int s = v0 + v1;
    int lane = tid & 63, w = tid >> 6;
    int x = s;
    #pragma unroll
    for (int off = 1; off < 64; off <<= 1) {
        int tmp = __shfl_up(x, off);
        if (lane >= off) x += tmp;
    }
    if (lane == 63) wsum[w] = x;
    __syncthreads();
    int waveoff = 0;
    for (int j = 0; j < w; ++j) waveoff += wsum[j];
    int excl = waveoff + x - s;
    if (b0 < NBLKP) goff[b0 * NBUCK + t] = excl;
    if (b1 < NBLKP) goff[b1 * NBUCK + t] = excl + v0;
    if (tid == 255) colsum[t] = waveoff + x;   // column total
}

// ---- partition step 2b: exclusive scan of 196 column sums -> bstart ----
__global__ __launch_bounds__(256) void k_poffB(const int* __restrict__ colsum, int* __restrict__ bstart) {
    __shared__ int wsum[4];
    int tid = threadIdx.x;
    int v = (tid < NBUCK) ? colsum[tid] : 0;
    int lane = tid & 63, w = tid >> 6;
    int x = v;
    #pragma unroll
    for (int off = 1; off < 64; off <<= 1) {
        int tmp = __shfl_up(x, off);
        if (lane >= off) x += tmp;
    }
    if (lane == 63) wsum[w] = x;
    __syncthreads();
    int waveoff = 0;
    for (int j = 0; j < w; ++j) waveoff += wsum[j];
    if (tid < NBUCK) bstart[tid] = waveoff + x - v;
    if (tid == 0) bstart[NBUCK] = NE;
}

// ---- partition step 3: append 4B records (dloc<<16 | src); global pos = bstart[bin]+goff ----
__global__ __launch_bounds__(256) void k_pscat(const int* __restrict__ src, const int* __restrict__ dst,
                                               const int* __restrict__ goff, const int* __restrict__ bstart,
                                               unsigned int* __restrict__ tmp) {
    __shared__ int lcur[NBUCK];
    __shared__ int bs[NBUCK];
    int tid = threadIdx.x;
    if (tid < NBUCK) { lcur[tid] = 0; bs[tid] = bstart[tid]; }
    __syncthreads();
    int base = blockIdx.x * EPB;
    const int* go = goff + blockIdx.x * NBUCK;
    for (int i = tid; i < EPB; i += 256) {
        int ed = base + i;
        if (ed < NE) {
            int d = dst[ed];
            int bin = d >> 8;
            int r = atomicAdd(&lcur[bin], 1);
            tmp[bs[bin] + go[bin] + r] = ((unsigned int)(d & 255) << 16) | (unsigned int)src[ed];
        }
    }
}

// ---- partition step 4: per-bucket counting sort by (dloc, src>>13) -> srcs + rowp ----
__global__ __launch_bounds__(256) void k_lsort(const unsigned int* __restrict__ tmp,
                                               const int* __restrict__ bstart,
                                               int* __restrict__ rowp, int* __restrict__ srcs) {
    __shared__ int lh[2048], lcur[2048];
    __shared__ int wsum[4];
    int b = blockIdx.x, tid = threadIdx.x;
    int base = bstart[b], cnt = bstart[b + 1] - base;
    #pragma unroll
    for (int j = 0; j < 8; ++j) lh[j * 256 + tid] = 0;
    __syncthreads();
    for (int i = tid; i < cnt; i += 256) {
        unsigned int rec = tmp[base + i];
        int key = ((int)(rec >> 16) << 3) | ((int)(rec & 0xFFFFu) >> 13);
        atomicAdd(&lh[key & 2047], 1);
    }
    __syncthreads();
    int local[8];
    int s = 0;
    #pragma unroll
    for (int j = 0; j < 8; ++j) { local[j] = s; s += lh[tid * 8 + j]; }
    int lane = tid & 63, w = tid >> 6;
    int x = s;
    #pragma unroll
    for (int off = 1; off < 64; off <<= 1) {
        int t2 = __shfl_up(x, off);
        if (lane >= off) x += t2;
    }
    if (lane == 63) wsum[w] = x;
    __syncthreads();
    int waveoff = 0;
    for (int j = 0; j < w; ++j) waveoff += wsum[j];
    int excl = waveoff + x - s;                 // start of dloc==tid segment
    #pragma unroll
    for (int j = 0; j < 8; ++j) lcur[tid * 8 + j] = excl + local[j];
    int d = (b << 8) + tid;
    if (d < NN) rowp[d] = base + excl;
    if (b == NBUCK - 1 && tid == 0) rowp[NN] = NE;
    __syncthreads();
    for (int i = tid; i < cnt; i += 256) {
        unsigned int rec = tmp[base + i];
        int srcv = (int)(rec & 0xFFFFu);
        int key = ((int)(rec >> 16) << 3) | (srcv >> 13);
        int p = atomicAdd(&lcur[key & 2047], 1);
        srcs[base + p] = srcv;
    }
}

// ---- aggregation: half-wave per node; lane owns 8 dims; 4-way consume, double-buffered loads ----
__global__ __launch_bounds__(256) void k_agg(const unsigned short* __restrict__ zb, const int* __restrict__ rowp,
                                             const int* __restrict__ srcs, const float* __restrict__ ssrc,
                                             const float* __restrict__ sdst,
                                             const float* __restrict__ h, const float* __restrict__ norm,
                                             float* __restrict__ out) {
    int wv = threadIdx.x >> 6, lane = threadIdx.x & 63;
    int half = lane >> 5;
    int l = lane & 31;
    int n = blockIdx.x * 8 + wv * 2 + half;
    if (n >= NN) return;
    int p0 = rowp[n], p1 = rowp[n + 1];
    int deg = p1 - p0;
    int hd = l >> 3;
    float sd = sdst[(n << 2) + hd];
    float a0 = 0.f, a1 = 0.f, a2 = 0.f, a3 = 0.f;
    float a4 = 0.f, a5 = 0.f, a6 = 0.f, a7 = 0.f;
    float b0 = 0.f, b1 = 0.f, b2 = 0.f, b3 = 0.f;
    float b4 = 0.f, b5 = 0.f, b6 = 0.f, b7 = 0.f;
    float denA = 0.f, denB = 0.f;
    int zoffl = l << 3;
    int i = 0;
    int s0, s1, s2, s3;
    float e0, e1, e2, e3;
    uint4 z0, z1, z2, z3;
    if (deg >= 4) {                      // preload batch 0
        s0 = srcs[p0];     s1 = srcs[p0 + 1];
        s2 = srcs[p0 + 2]; s3 = srcs[p0 + 3];
        e0 = ssrc[(s0 << 2) + hd]; e1 = ssrc[(s1 << 2) + hd];
        e2 = ssrc[(s2 << 2) + hd]; e3 = ssrc[(s3 << 2) + hd];
        z0 = *(const uint4*)(zb + (s0 << 8) + zoffl);
        z1 = *(const uint4*)(zb + (s1 << 8) + zoffl);
        z2 = *(const uint4*)(zb + (s2 << 8) + zoffl);
        z3 = *(const uint4*)(zb + (s3 << 8) + zoffl);
    }
    for (; i + 8 <= deg; i += 4) {
        float f0 = e0, f1 = e1, f2 = e2, f3 = e3;
        uint4 y0 = z0, y1 = z1, y2 = z2, y3 = z3;
        int q = p0 + i + 4;              // issue next batch before consuming
        s0 = srcs[q];     s1 = srcs[q + 1];
        s2 = srcs[q + 2]; s3 = srcs[q + 3];
        e0 = ssrc[(s0 << 2) + hd]; e1 = ssrc[(s1 << 2) + hd];
        e2 = ssrc[(s2 << 2) + hd]; e3 = ssrc[(s3 << 2) + hd];
        z0 = *(const uint4*)(zb + (s0 << 8) + zoffl);
        z1 = *(const uint4*)(zb + (s1 << 8) + zoffl);
        z2 = *(const uint4*)(zb + (s2 << 8) + zoffl);
        z3 = *(const uint4*)(zb + (s3 << 8) + zoffl);
        float w0 = __expf(f0 + sd);
        float w1 = __expf(f1 + sd);
        float w2 = __expf(f2 + sd);
        float w3 = __expf(f3 + sd);
        a0 += w0 * bf2f((unsigned short)(y0.x & 0xFFFFu));
        a1 += w0 * bf2f((unsigned short)(y0.x >> 16));
        a2 += w0 * bf2f((unsigned short)(y0.y & 0xFFFFu));
        a3 += w0 * bf2f((unsigned short)(y0.y >> 16));
        a4 += w0 * bf2f((unsigned short)(y0.z & 0xFFFFu));
        a5 += w0 * bf2f((unsigned short)(y0.z >> 16));
        a6 += w0 * bf2f((unsigned short)(y0.w & 0xFFFFu));
        a7 += w0 * bf2f((unsigned short)(y0.w >> 16));
        denA += w0;
        b0 += w1 * bf2f((unsigned short)(y1.x & 0xFFFFu));
        b1 += w1 * bf2f((unsigned short)(y1.x >> 16));
        b2 += w1 * bf2f((unsigned short)(y1.y & 0xFFFFu));
        b3 += w1 * bf2f((unsigned short)(y1.y >> 16));
        b4 += w1 * bf2f((unsigned short)(y1.z & 0xFFFFu));
        b5 += w1 * bf2f((unsigned short)(y1.z >> 16));
        b6 += w1 * bf2f((unsigned short)(y1.w & 0xFFFFu));
        b7 += w1 * bf2f((unsigned short)(y1.w >> 16));
        denB += w1;
        a0 += w2 * bf2f((unsigned short)(y2.x & 0xFFFFu));
        a1 += w2 * bf2f((unsigned short)(y2.x >> 16));
        a2 += w2 * bf2f((unsigned short)(y2.y & 0xFFFFu));
        a3 += w2 * bf2f((unsigned short)(y2.y >> 16));
        a4 += w2 * bf2f((unsigned short)(y2.z & 0xFFFFu));
        a5 += w2 * bf2f((unsigned short)(y2.z >> 16));
        a6 += w2 * bf2f((unsigned short)(y2.w & 0xFFFFu));
        a7 += w2 * bf2f((unsigned short)(y2.w >> 16));
        denA += w2;
        b0 += w3 * bf2f((unsigned short)(y3.x & 0xFFFFu));
        b1 += w3 * bf2f((unsigned short)(y3.x >> 16));
        b2 += w3 * bf2f((unsigned short)(y3.y & 0xFFFFu));
        b3 += w3 * bf2f((unsigned short)(y3.y >> 16));
        b4 += w3 * bf2f((unsigned short)(y3.z & 0xFFFFu));
        b5 += w3 * bf2f((unsigned short)(y3.z >> 16));
        b6 += w3 * bf2f((unsigned short)(y3.w & 0xFFFFu));
        b7 += w3 * bf2f((unsigned short)(y3.w >> 16));
        denB += w3;
    }
    if (deg >= 4) {                      // drain the last loaded batch
        float w0 = __expf(e0 + sd);
        float w1 = __expf(e1 + sd);
        float w2 = __expf(e2 + sd);
        float w3 = __expf(e3 + sd);
        a0 += w0 * bf2f((unsigned short)(z0.x & 0xFFFFu));
        a1 += w0 * bf2f((unsigned short)(z0.x >> 16));
        a2 += w0 * bf2f((unsigned short)(z0.y & 0xFFFFu));
        a3 += w0 * bf2f((unsigned short)(z0.y >> 16));
        a4 += w0 * bf2f((unsigned short)(z0.z & 0xFFFFu));
        a5 += w0 * bf2f((unsigned short)(z0.z >> 16));
        a6 += w0 * bf2f((unsigned short)(z0.w & 0xFFFFu));
        a7 += w0 * bf2f((unsigned short)(z0.w >> 16));
        denA += w0;
        b0 += w1 * bf2f((unsigned short)(z1.x & 0xFFFFu));
        b1 += w1 * bf2f((unsigned short)(z1.x >> 16));
        b2 += w1 * bf2f((unsigned short)(z1.y & 0xFFFFu));
        b3 += w1 * bf2f((unsigned short)(z1.y >> 16));
        b4 += w1 * bf2f((unsigned short)(z1.z & 0xFFFFu));
        b5 += w1 * bf2f((unsigned short)(z1.z >> 16));
        b6 += w1 * bf2f((unsigned short)(z1.w & 0xFFFFu));
        b7 += w1 * bf2f((unsigned short)(z1.w >> 16));
        denB += w1;
        a0 += w2 * bf2f((unsigned short)(z2.x & 0xFFFFu));
        a1 += w2 * bf2f((unsigned short)(z2.x >> 16));
        a2 += w2 * bf2f((unsigned short)(z2.y & 0xFFFFu));
        a3 += w2 * bf2f((unsigned short)(z2.y >> 16));
        a4 += w2 * bf2f((unsigned short)(z2.z & 0xFFFFu));
        a5 += w2 * bf2f((unsigned short)(z2.z >> 16));
        a6 += w2 * bf2f((unsigned short)(z2.w & 0xFFFFu));
        a7 += w2 * bf2f((unsigned short)(z2.w >> 16));
        denA += w2;
        b0 += w3 * bf2f((unsigned short)(z3.x & 0xFFFFu));
        b1 += w3 * bf2f((unsigned short)(z3.x >> 16));
        b2 += w3 * bf2f((unsigned short)(z3.y & 0xFFFFu));
        b3 += w3 * bf2f((unsigned short)(z3.y >> 16));
        b4 += w3 * bf2f((unsigned short)(z3.z & 0xFFFFu));
        b5 += w3 * bf2f((unsigned short)(z3.z >> 16));
        b6 += w3 * bf2f((unsigned short)(z3.w & 0xFFFFu));
        b7 += w3 * bf2f((unsigned short)(z3.w >> 16));
        denB += w3;
        i += 4;
    }
    for (; i < deg; ++i) {
        int st = srcs[p0 + i];
        float w0 = __expf(ssrc[(st << 2) + hd] + sd);
        uint4 zt = *(const uint4*)(zb + (st << 8) + zoffl);
        a0 += w0 * bf2f((unsigned short)(zt.x & 0xFFFFu));
        a1 += w0 * bf2f((unsigned short)(zt.x >> 16));
        a2 += w0 * bf2f((unsigned short)(zt.y & 0xFFFFu));
        a3 += w0 * bf2f((unsigned short)(zt.y >> 16));
        a4 += w0 * bf2f((unsigned short)(zt.z & 0xFFFFu));
        a5 += w0 * bf2f((unsigned short)(zt.z >> 16));
        a6 += w0 * bf2f((unsigned short)(zt.w & 0xFFFFu));
        a7 += w0 * bf2f((unsigned short)(zt.w >> 16));
        denA += w0;
    }
    a0 += b0; a1 += b1; a2 += b2; a3 += b3;
    a4 += b4; a5 += b5; a6 += b6; a7 += b7;
    float den = denA + denB;
    float nm = norm[n];
    float inv = (deg > 0) ? nm / den : 0.f;
    size_t bofs = (size_t)n * IND + zoffl;
    float4 h0 = *(const float4*)(h + bofs);
    float4 h1 = *(const float4*)(h + bofs + 4);
    float4 o0, o1;
    o0.x = h0.x + inv * a0; o0.y = h0.y + inv * a1;
    o0.z = h0.z + inv * a2; o0.w = h0.w + inv * a3;
    o1.x = h1.x + inv * a4; o1.y = h1.y + inv * a5;
    o1.z = h1.z + inv * a6; o1.w = h1.w + inv * a7;
    *(float4*)(out + bofs) = o0;
    *(float4*)(out + bofs + 4) = o1;
}

extern "C" void kernel_launch(void* const* d_in, const int* in_sizes, int n_in,
                              void* d_out, int out_size, void* d_ws, size_t ws_size,
                              hipStream_t stream) {
    const float* h    = (const float*)d_in[0];
    const float* e    = (const float*)d_in[1];
    const float* norm = (const float*)d_in[2];
    const int*   src  = (const int*)d_in[3];
    const int*   dst  = (const int*)d_in[4];
    const float* W    = (const float*)d_in[5];
    const float* a    = (const float*)d_in[6];
    float* out = (float*)d_out;

    char* p = (char*)d_ws;
    unsigned short* Wtf = (unsigned short*)p; p += 262144;
    unsigned short* zb = (unsigned short*)p; p += 25600000;   // N*256*2
    unsigned short* hbf = (unsigned short*)p; p += 25600000;  // fragment-major bf16(h*norm)
    float* ssrc = (float*)p; p += 800000;
    float* sdst = (float*)p; p += 800000;
    int*   rowp = (int*)p;   p += 200192;
    int*   srcs = (int*)p;   p += 6400000;
    int*   bh   = (int*)p;   p += 307200;     // NBLKP*NBUCK ints
    int*   goff = (int*)p;   p += 307200;
    int*   bstart = (int*)p; p += 4096;
    int*   colsum = (int*)p; p += 4096;
    unsigned int* tmp = (unsigned int*)p; p += 6400000;  // NE*4 (packed records)

    k_wt<<<256, 256, 0, stream>>>(W, Wtf, (const float4*)e, (float4*)(out + (size_t)NN * IND));
    k_conv<<<6250, 256, 0, stream>>>(h, norm, hbf);
    k_gmm<<<1563, 256, 0, stream>>>(hbf, Wtf, a, zb, ssrc, sdst);
    k_phist<<<NBLKP, 256, 0, stream>>>(dst, bh);
    k_poffA<<<NBUCK, 256, 0, stream>>>(bh, goff, colsum);
    k_poffB<<<1, 256, 0, stream>>>(colsum, bstart);
    k_pscat<<<NBLKP, 256, 0, stream>>>(src, dst, goff, bstart, tmp);
    k_lsort<<<NBUCK, 256, 0, stream>>>(tmp, bstart, rowp, srcs);
    k_agg<<<6250, 256, 0, stream>>>(zb, rowp, srcs, ssrc, sdst, h, norm, out);
}

// Round 27
// 199.874 us; speedup vs baseline: 1.0433x; 1.0433x over previous
//
#include <hip/hip_runtime.h>

#define NN 50000
#define NE 1600000
#define IND 256
#define OUTD 64
#define NH 4
#define EPB 4096
#define NBLKP 391   // ceil(NE/EPB)
#define NBUCK 196   // ceil(NN/256)

typedef __attribute__((ext_vector_type(8))) short short8;
typedef __attribute__((ext_vector_type(4))) float f32x4;

__device__ __forceinline__ unsigned short f2bf(float x) {
    unsigned int u = __float_as_uint(x);
    u = (u + 0x7FFFu + ((u >> 16) & 1u)) >> 16;   // RNE
    return (unsigned short)u;
}
__device__ __forceinline__ float bf2f(unsigned short u) {
    return __uint_as_float((unsigned int)u << 16);
}

// ---- Wtf[hd][nt][ks][lane][e] = bf16(W[hd][ks*32+(lane>>4)*8+e][nt*16+(lane&15)]) ----
__global__ __launch_bounds__(256) void k_wt(const float* __restrict__ W, unsigned short* __restrict__ Wtf,
                                            const float4* __restrict__ e4, float4* __restrict__ oute4) {
    int t = blockIdx.x * 256 + threadIdx.x;       // 65536
    int e = t & 7;
    int lane = (t >> 3) & 63;
    int ks = (t >> 9) & 7;
    int nt = (t >> 12) & 3;
    int hd = (t >> 14) & 3;
    int k = ks * 32 + (lane >> 4) * 8 + e;
    int d = nt * 16 + (lane & 15);
    Wtf[t] = f2bf(W[hd * IND * OUTD + k * OUTD + d]);
    for (int i = t; i < NE / 4; i += 65536) oute4[i] = e4[i];
}

// ---- fused GEMM: BM=32, LDS-staged A (coalesced), fragment-major B (coalesced) ----
__global__ __launch_bounds__(256) void k_gmm(const float* __restrict__ h, const float* __restrict__ norm,
                                             const unsigned short* __restrict__ Wtf, const float* __restrict__ a,
                                             unsigned short* __restrict__ zb,
                                             float* __restrict__ ssrc, float* __restrict__ sdst) {
    __shared__ unsigned short ldsA[32 * 264];     // 32 rows x 264 shorts (528B stride)
    __shared__ unsigned short ldsE[4][16 * 80];   // epilogue transpose
    const int tid = threadIdx.x;
    const int lane = tid & 63;
    const int wv = tid >> 6;                      // head index
    const int m0 = blockIdx.x * 32;
    const int c0 = wv * 64;
    const int r16 = lane & 15, kg = lane >> 4;

    #pragma unroll
    for (int q = 0; q < 4; ++q) {
        int idx = q * 2048 + tid * 8;
        int row = idx >> 8, col = idx & 255;
        int grow = m0 + row; if (grow > NN - 1) grow = NN - 1;
        float nmv = norm[grow];
        const float4* hp = (const float4*)(h + (size_t)grow * IND + col);
        float4 x0 = hp[0], x1 = hp[1];
        short8 r;
        r[0] = (short)f2bf(x0.x * nmv); r[1] = (short)f2bf(x0.y * nmv);
        r[2] = (short)f2bf(x0.z * nmv); r[3] = (short)f2bf(x0.w * nmv);
        r[4] = (short)f2bf(x1.x * nmv); r[5] = (short)f2bf(x1.y * nmv);
        r[6] = (short)f2bf(x1.z * nmv); r[7] = (short)f2bf(x1.w * nmv);
        *(short8*)&ldsA[row * 264 + col] = r;
    }
    __syncthreads();

    const short8* bfp = (const short8*)(Wtf) + (size_t)wv * 4 * 8 * 64;   // head base, fragment-major

    f32x4 acc[2][4] = {};
    #pragma unroll
    for (int ks = 0; ks < 8; ++ks) {
        short8 av0 = *(const short8*)&ldsA[r16 * 264 + ks * 32 + kg * 8];
        short8 av1 = *(const short8*)&ldsA[(16 + r16) * 264 + ks * 32 + kg * 8];
        #pragma unroll
        for (int nt = 0; nt < 4; ++nt) {
            short8 cb = bfp[(nt * 8 + ks) * 64 + lane];
            acc[0][nt] = __builtin_amdgcn_mfma_f32_16x16x32_bf16(av0, cb, acc[0][nt], 0, 0, 0);
            acc[1][nt] = __builtin_amdgcn_mfma_f32_16x16x32_bf16(av1, cb, acc[1][nt], 0, 0, 0);
        }
    }

    float asrc[4], adst[4];
    #pragma unroll
    for (int j = 0; j < 4; ++j) {
        asrc[j] = a[wv * 128 + j * 16 + r16];
        adst[j] = a[wv * 128 + 64 + j * 16 + r16];
    }
    #pragma unroll
    for (int mt = 0; mt < 2; ++mt) {
        #pragma unroll
        for (int r = 0; r < 4; ++r) {
            int row = m0 + mt * 16 + kg * 4 + r;  // D: row=(lane>>4)*4+reg, col=lane&15
            unsigned short q0 = f2bf(acc[mt][0][r]);
            unsigned short q1 = f2bf(acc[mt][1][r]);
            unsigned short q2 = f2bf(acc[mt][2][r]);
            unsigned short q3 = f2bf(acc[mt][3][r]);
            float ps = bf2f(q0) * asrc[0] + bf2f(q1) * asrc[1] + bf2f(q2) * asrc[2] + bf2f(q3) * asrc[3];
            float pd = bf2f(q0) * adst[0] + bf2f(q1) * adst[1] + bf2f(q2) * adst[2] + bf2f(q3) * adst[3];
            #pragma unroll
            for (int off = 1; off < 16; off <<= 1) {
                ps += __shfl_xor(ps, off);
                pd += __shfl_xor(pd, off);
            }
            unsigned short* lp = &ldsE[wv][(kg * 4 + r) * 80];
            lp[ 0 + r16] = q0;
            lp[16 + r16] = q1;
            lp[32 + r16] = q2;
            lp[48 + r16] = q3;
            if (row < NN && r16 == 0) {
                ssrc[(row << 2) + wv] = ps;
                sdst[(row << 2) + wv] = pd;
            }
        }
        asm volatile("s_waitcnt lgkmcnt(0)" ::: "memory");
        __builtin_amdgcn_sched_barrier(0);
        #pragma unroll
        for (int hf = 0; hf < 2; ++hf) {
            int lrow = hf * 8 + (lane >> 3);
            int chunk = lane & 7;
            short8 v = *(const short8*)&ldsE[wv][lrow * 80 + chunk * 8];
            int grow = m0 + mt * 16 + lrow;
            if (grow < NN)
                *(short8*)(zb + (size_t)grow * IND + c0 + chunk * 8) = v;
        }
        __builtin_amdgcn_sched_barrier(0);
    }
}

// ---- partition step 1: per-block histogram over 196 coarse buckets (dst>>8) ----
__global__ __launch_bounds__(256) void k_phist(const int* __restrict__ dst, int* __restrict__ bh) {
    __shared__ int lh[NBUCK];
    int tid = threadIdx.x;
    if (tid < NBUCK) lh[tid] = 0;
    __syncthreads();
    int base = blockIdx.x * EPB;
    for (int i = tid; i < EPB; i += 256) {
        int ed = base + i;
        if (ed < NE) atomicAdd(&lh[dst[ed] >> 8], 1);
    }
    __syncthreads();
    if (tid < NBUCK) bh[blockIdx.x * NBUCK + tid] = lh[tid];
}

// ---- partition step 2a: per-bucket column scan (196 blocks, parallel) ----
__global__ __launch_bounds__(256) void k_poffA(const int* __restrict__ bh, int* __restrict__ goff,
                                               int* __restrict__ colsum) {
    __shared__ int wsum[4];
    int t = blockIdx.x;                        // bucket
    int tid = threadIdx.x;
    int b0 = tid * 2, b1 = tid * 2 + 1;
    int v0 = (b0 < NBLKP) ? bh[b0 * NBUCK + t] : 0;
    int v1 = (b1 < NBLKP) ? bh[b1 * NBUCK + t] : 0;
    int s = v0 + v1;
    int lane = tid & 63, w = tid >> 6;
    int x = s;
    #pragma unroll
    for (int off = 1; off < 64; off <<= 1) {
        int tmp = __shfl_up(x, off);
        if (lane >= off) x += tmp;
    }
    if (lane == 63) wsum[w] = x;
    __syncthreads();
    int waveoff = 0;
    for (int j = 0; j < w; ++j) waveoff += wsum[j];
    int excl = waveoff + x - s;
    if (b0 < NBLKP) goff[b0 * NBUCK + t] = excl;
    if (b1 < NBLKP) goff[b1 * NBUCK + t] = excl + v0;
    if (tid == 255) colsum[t] = waveoff + x;   // column total
}

// ---- partition step 2b: exclusive scan of 196 column sums -> bstart ----
__global__ __launch_bounds__(256) void k_poffB(const int* __restrict__ colsum, int* __restrict__ bstart) {
    __shared__ int wsum[4];
    int tid = threadIdx.x;
    int v = (tid < NBUCK) ? colsum[tid] : 0;
    int lane = tid & 63, w = tid >> 6;
    int x = v;
    #pragma unroll
    for (int off = 1; off < 64; off <<= 1) {
        int tmp = __shfl_up(x, off);
        if (lane >= off) x += tmp;
    }
    if (lane == 63) wsum[w] = x;
    __syncthreads();
    int waveoff = 0;
    for (int j = 0; j < w; ++j) waveoff += wsum[j];
    if (tid < NBUCK) bstart[tid] = waveoff + x - v;
    if (tid == 0) bstart[NBUCK] = NE;
}

// ---- partition step 3: append 4B records (dloc<<16 | src); global pos = bstart[bin]+goff ----
__global__ __launch_bounds__(256) void k_pscat(const int* __restrict__ src, const int* __restrict__ dst,
                                               const int* __restrict__ goff, const int* __restrict__ bstart,
                                               unsigned int* __restrict__ tmp) {
    __shared__ int lcur[NBUCK];
    __shared__ int bs[NBUCK];
    int tid = threadIdx.x;
    if (tid < NBUCK) { lcur[tid] = 0; bs[tid] = bstart[tid]; }
    __syncthreads();
    int base = blockIdx.x * EPB;
    const int* go = goff + blockIdx.x * NBUCK;
    for (int i = tid; i < EPB; i += 256) {
        int ed = base + i;
        if (ed < NE) {
            int d = dst[ed];
            int bin = d >> 8;
            int r = atomicAdd(&lcur[bin], 1);
            tmp[bs[bin] + go[bin] + r] = ((unsigned int)(d & 255) << 16) | (unsigned int)src[ed];
        }
    }
}

// ---- partition step 4: per-bucket counting sort by (dloc, src>>13) -> srcs + rowp ----
// 2048 bins = dloc-major, 8 coarse src phases -> phased gather locality in k_agg
__global__ __launch_bounds__(256) void k_lsort(const unsigned int* __restrict__ tmp,
                                               const int* __restrict__ bstart,
                                               int* __restrict__ rowp, int* __restrict__ srcs) {
    __shared__ int lh[2048], lcur[2048];
    __shared__ int wsum[4];
    int b = blockIdx.x, tid = threadIdx.x;
    int base = bstart[b], cnt = bstart[b + 1] - base;
    #pragma unroll
    for (int j = 0; j < 8; ++j) lh[j * 256 + tid] = 0;
    __syncthreads();
    for (int i = tid; i < cnt; i += 256) {
        unsigned int rec = tmp[base + i];
        int key = ((int)(rec >> 16) << 3) | ((int)(rec & 0xFFFFu) >> 13);
        atomicAdd(&lh[key & 2047], 1);
    }
    __syncthreads();
    // thread tid owns bins tid*8..tid*8+7 (exactly dloc==tid's 8 phase bins)
    int local[8];
    int s = 0;
    #pragma unroll
    for (int j = 0; j < 8; ++j) { local[j] = s; s += lh[tid * 8 + j]; }
    int lane = tid & 63, w = tid >> 6;
    int x = s;
    #pragma unroll
    for (int off = 1; off < 64; off <<= 1) {
        int t2 = __shfl_up(x, off);
        if (lane >= off) x += t2;
    }
    if (lane == 63) wsum[w] = x;
    __syncthreads();
    int waveoff = 0;
    for (int j = 0; j < w; ++j) waveoff += wsum[j];
    int excl = waveoff + x - s;                 // start of dloc==tid segment
    #pragma unroll
    for (int j = 0; j < 8; ++j) lcur[tid * 8 + j] = excl + local[j];
    int d = (b << 8) + tid;
    if (d < NN) rowp[d] = base + excl;
    if (b == NBUCK - 1 && tid == 0) rowp[NN] = NE;
    __syncthreads();
    for (int i = tid; i < cnt; i += 256) {
        unsigned int rec = tmp[base + i];
        int srcv = (int)(rec & 0xFFFFu);
        int key = ((int)(rec >> 16) << 3) | (srcv >> 13);
        int p = atomicAdd(&lcur[key & 2047], 1);
        srcs[base + p] = srcv;
    }
}

// ---- aggregation: half-wave per node; lane owns 8 dims; 4-way consume, double-buffered loads ----
__global__ __launch_bounds__(256) void k_agg(const unsigned short* __restrict__ zb, const int* __restrict__ rowp,
                                             const int* __restrict__ srcs, const float* __restrict__ ssrc,
                                             const float* __restrict__ sdst,
                                             const float* __restrict__ h, const float* __restrict__ norm,
                                             float* __restrict__ out) {
    int wv = threadIdx.x >> 6, lane = threadIdx.x & 63;
    int half = lane >> 5;
    int l = lane & 31;
    int n = blockIdx.x * 8 + wv * 2 + half;
    if (n >= NN) return;
    int p0 = rowp[n], p1 = rowp[n + 1];
    int deg = p1 - p0;
    int hd = l >> 3;
    float sd = sdst[(n << 2) + hd];
    float a0 = 0.f, a1 = 0.f, a2 = 0.f, a3 = 0.f;
    float a4 = 0.f, a5 = 0.f, a6 = 0.f, a7 = 0.f;
    float b0 = 0.f, b1 = 0.f, b2 = 0.f, b3 = 0.f;
    float b4 = 0.f, b5 = 0.f, b6 = 0.f, b7 = 0.f;
    float denA = 0.f, denB = 0.f;
    int zoffl = l << 3;
    int i = 0;
    int s0, s1, s2, s3;
    float e0, e1, e2, e3;
    uint4 z0, z1, z2, z3;
    if (deg >= 4) {                      // preload batch 0
        s0 = srcs[p0];     s1 = srcs[p0 + 1];
        s2 = srcs[p0 + 2]; s3 = srcs[p0 + 3];
        e0 = ssrc[(s0 << 2) + hd]; e1 = ssrc[(s1 << 2) + hd];
        e2 = ssrc[(s2 << 2) + hd]; e3 = ssrc[(s3 << 2) + hd];
        z0 = *(const uint4*)(zb + (s0 << 8) + zoffl);
        z1 = *(const uint4*)(zb + (s1 << 8) + zoffl);
        z2 = *(const uint4*)(zb + (s2 << 8) + zoffl);
        z3 = *(const uint4*)(zb + (s3 << 8) + zoffl);
    }
    for (; i + 8 <= deg; i += 4) {
        float f0 = e0, f1 = e1, f2 = e2, f3 = e3;
        uint4 y0 = z0, y1 = z1, y2 = z2, y3 = z3;
        int q = p0 + i + 4;              // issue next batch before consuming
        s0 = srcs[q];     s1 = srcs[q + 1];
        s2 = srcs[q + 2]; s3 = srcs[q + 3];
        e0 = ssrc[(s0 << 2) + hd]; e1 = ssrc[(s1 << 2) + hd];
        e2 = ssrc[(s2 << 2) + hd]; e3 = ssrc[(s3 << 2) + hd];
        z0 = *(const uint4*)(zb + (s0 << 8) + zoffl);
        z1 = *(const uint4*)(zb + (s1 << 8) + zoffl);
        z2 = *(const uint4*)(zb + (s2 << 8) + zoffl);
        z3 = *(const uint4*)(zb + (s3 << 8) + zoffl);
        float w0 = __expf(f0 + sd);
        float w1 = __expf(f1 + sd);
        float w2 = __expf(f2 + sd);
        float w3 = __expf(f3 + sd);
        a0 += w0 * bf2f((unsigned short)(y0.x & 0xFFFFu));
        a1 += w0 * bf2f((unsigned short)(y0.x >> 16));
        a2 += w0 * bf2f((unsigned short)(y0.y & 0xFFFFu));
        a3 += w0 * bf2f((unsigned short)(y0.y >> 16));
        a4 += w0 * bf2f((unsigned short)(y0.z & 0xFFFFu));
        a5 += w0 * bf2f((unsigned short)(y0.z >> 16));
        a6 += w0 * bf2f((unsigned short)(y0.w & 0xFFFFu));
        a7 += w0 * bf2f((unsigned short)(y0.w >> 16));
        denA += w0;
        b0 += w1 * bf2f((unsigned short)(y1.x & 0xFFFFu));
        b1 += w1 * bf2f((unsigned short)(y1.x >> 16));
        b2 += w1 * bf2f((unsigned short)(y1.y & 0xFFFFu));
        b3 += w1 * bf2f((unsigned short)(y1.y >> 16));
        b4 += w1 * bf2f((unsigned short)(y1.z & 0xFFFFu));
        b5 += w1 * bf2f((unsigned short)(y1.z >> 16));
        b6 += w1 * bf2f((unsigned short)(y1.w & 0xFFFFu));
        b7 += w1 * bf2f((unsigned short)(y1.w >> 16));
        denB += w1;
        a0 += w2 * bf2f((unsigned short)(y2.x & 0xFFFFu));
        a1 += w2 * bf2f((unsigned short)(y2.x >> 16));
        a2 += w2 * bf2f((unsigned short)(y2.y & 0xFFFFu));
        a3 += w2 * bf2f((unsigned short)(y2.y >> 16));
        a4 += w2 * bf2f((unsigned short)(y2.z & 0xFFFFu));
        a5 += w2 * bf2f((unsigned short)(y2.z >> 16));
        a6 += w2 * bf2f((unsigned short)(y2.w & 0xFFFFu));
        a7 += w2 * bf2f((unsigned short)(y2.w >> 16));
        denA += w2;
        b0 += w3 * bf2f((unsigned short)(y3.x & 0xFFFFu));
        b1 += w3 * bf2f((unsigned short)(y3.x >> 16));
        b2 += w3 * bf2f((unsigned short)(y3.y & 0xFFFFu));
        b3 += w3 * bf2f((unsigned short)(y3.y >> 16));
        b4 += w3 * bf2f((unsigned short)(y3.z & 0xFFFFu));
        b5 += w3 * bf2f((unsigned short)(y3.z >> 16));
        b6 += w3 * bf2f((unsigned short)(y3.w & 0xFFFFu));
        b7 += w3 * bf2f((unsigned short)(y3.w >> 16));
        denB += w3;
    }
    if (deg >= 4) {                      // drain the last loaded batch
        float w0 = __expf(e0 + sd);
        float w1 = __expf(e1 + sd);
        float w2 = __expf(e2 + sd);
        float w3 = __expf(e3 + sd);
        a0 += w0 * bf2f((unsigned short)(z0.x & 0xFFFFu));
        a1 += w0 * bf2f((unsigned short)(z0.x >> 16));
        a2 += w0 * bf2f((unsigned short)(z0.y & 0xFFFFu));
        a3 += w0 * bf2f((unsigned short)(z0.y >> 16));
        a4 += w0 * bf2f((unsigned short)(z0.z & 0xFFFFu));
        a5 += w0 * bf2f((unsigned short)(z0.z >> 16));
        a6 += w0 * bf2f((unsigned short)(z0.w & 0xFFFFu));
        a7 += w0 * bf2f((unsigned short)(z0.w >> 16));
        denA += w0;
        b0 += w1 * bf2f((unsigned short)(z1.x & 0xFFFFu));
        b1 += w1 * bf2f((unsigned short)(z1.x >> 16));
        b2 += w1 * bf2f((unsigned short)(z1.y & 0xFFFFu));
        b3 += w1 * bf2f((unsigned short)(z1.y >> 16));
        b4 += w1 * bf2f((unsigned short)(z1.z & 0xFFFFu));
        b5 += w1 * bf2f((unsigned short)(z1.z >> 16));
        b6 += w1 * bf2f((unsigned short)(z1.w & 0xFFFFu));
        b7 += w1 * bf2f((unsigned short)(z1.w >> 16));
        denB += w1;
        a0 += w2 * bf2f((unsigned short)(z2.x & 0xFFFFu));
        a1 += w2 * bf2f((unsigned short)(z2.x >> 16));
        a2 += w2 * bf2f((unsigned short)(z2.y & 0xFFFFu));
        a3 += w2 * bf2f((unsigned short)(z2.y >> 16));
        a4 += w2 * bf2f((unsigned short)(z2.z & 0xFFFFu));
        a5 += w2 * bf2f((unsigned short)(z2.z >> 16));
        a6 += w2 * bf2f((unsigned short)(z2.w & 0xFFFFu));
        a7 += w2 * bf2f((unsigned short)(z2.w >> 16));
        denA += w2;
        b0 += w3 * bf2f((unsigned short)(z3.x & 0xFFFFu));
        b1 += w3 * bf2f((unsigned short)(z3.x >> 16));
        b2 += w3 * bf2f((unsigned short)(z3.y & 0xFFFFu));
        b3 += w3 * bf2f((unsigned short)(z3.y >> 16));
        b4 += w3 * bf2f((unsigned short)(z3.z & 0xFFFFu));
        b5 += w3 * bf2f((unsigned short)(z3.z >> 16));
        b6 += w3 * bf2f((unsigned short)(z3.w & 0xFFFFu));
        b7 += w3 * bf2f((unsigned short)(z3.w >> 16));
        denB += w3;
        i += 4;
    }
    for (; i < deg; ++i) {
        int st = srcs[p0 + i];
        float w0 = __expf(ssrc[(st << 2) + hd] + sd);
        uint4 zt = *(const uint4*)(zb + (st << 8) + zoffl);
        a0 += w0 * bf2f((unsigned short)(zt.x & 0xFFFFu));
        a1 += w0 * bf2f((unsigned short)(zt.x >> 16));
        a2 += w0 * bf2f((unsigned short)(zt.y & 0xFFFFu));
        a3 += w0 * bf2f((unsigned short)(zt.y >> 16));
        a4 += w0 * bf2f((unsigned short)(zt.z & 0xFFFFu));
        a5 += w0 * bf2f((unsigned short)(zt.z >> 16));
        a6 += w0 * bf2f((unsigned short)(zt.w & 0xFFFFu));
        a7 += w0 * bf2f((unsigned short)(zt.w >> 16));
        denA += w0;
    }
    a0 += b0; a1 += b1; a2 += b2; a3 += b3;
    a4 += b4; a5 += b5; a6 += b6; a7 += b7;
    float den = denA + denB;
    float nm = norm[n];
    float inv = (deg > 0) ? nm / den : 0.f;
    size_t bofs = (size_t)n * IND + zoffl;
    float4 h0 = *(const float4*)(h + bofs);
    float4 h1 = *(const float4*)(h + bofs + 4);
    float4 o0, o1;
    o0.x = h0.x + inv * a0; o0.y = h0.y + inv * a1;
    o0.z = h0.z + inv * a2; o0.w = h0.w + inv * a3;
    o1.x = h1.x + inv * a4; o1.y = h1.y + inv * a5;
    o1.z = h1.z + inv * a6; o1.w = h1.w + inv * a7;
    *(float4*)(out + bofs) = o0;
    *(float4*)(out + bofs + 4) = o1;
}

extern "C" void kernel_launch(void* const* d_in, const int* in_sizes, int n_in,
                              void* d_out, int out_size, void* d_ws, size_t ws_size,
                              hipStream_t stream) {
    const float* h    = (const float*)d_in[0];
    const float* e    = (const float*)d_in[1];
    const float* norm = (const float*)d_in[2];
    const int*   src  = (const int*)d_in[3];
    const int*   dst  = (const int*)d_in[4];
    const float* W    = (const float*)d_in[5];
    const float* a    = (const float*)d_in[6];
    float* out = (float*)d_out;

    char* p = (char*)d_ws;
    unsigned short* Wtf = (unsigned short*)p; p += 262144;
    unsigned short* zb = (unsigned short*)p; p += 25600000;   // N*256*2
    float* ssrc = (float*)p; p += 800000;
    float* sdst = (float*)p; p += 800000;
    int*   rowp = (int*)p;   p += 200192;
    int*   srcs = (int*)p;   p += 6400000;
    int*   bh   = (int*)p;   p += 307200;     // NBLKP*NBUCK ints
    int*   goff = (int*)p;   p += 307200;
    int*   bstart = (int*)p; p += 4096;
    int*   colsum = (int*)p; p += 4096;
    unsigned int* tmp = (unsigned int*)p; p += 6400000;  // NE*4 (packed records)

    k_wt<<<256, 256, 0, stream>>>(W, Wtf, (const float4*)e, (float4*)(out + (size_t)NN * IND));
    k_gmm<<<1563, 256, 0, stream>>>(h, norm, Wtf, a, zb, ssrc, sdst);
    k_phist<<<NBLKP, 256, 0, stream>>>(dst, bh);
    k_poffA<<<NBUCK, 256, 0, stream>>>(bh, goff, colsum);
    k_poffB<<<1, 256, 0, stream>>>(colsum, bstart);
    k_pscat<<<NBLKP, 256, 0, stream>>>(src, dst, goff, bstart, tmp);
    k_lsort<<<NBUCK, 256, 0, stream>>>(tmp, bstart, rowp, srcs);
    k_agg<<<6250, 256, 0, stream>>>(zb, rowp, srcs, ssrc, sdst, h, norm, out);
}